// Round 9
// baseline (335.813 us; speedup 1.0000x reference)
//
#include <hip/hip_runtime.h>
#include <hip/hip_bf16.h>

#define B_  32
#define T_  1024
#define C_  8
#define K_  10
#define LH_ 32

// ---------------------------------------------------------------------------
// workspace layout (floats)
// ---------------------------------------------------------------------------
#define WS_H    0
#define WS_SQ   1048576            // B*T*32
#define WS_ACC  (WS_SQ + 32768)
#define WS_WT   (WS_ACC + 1024)   // transposed weights, 106496 floats
#define WS_A0   (WS_WT + 106496)  // [B][27][32]
#define WS_O0   (WS_A0 + 27648)   // [B][25][32]
#define WS_A1   (WS_O0 + 25600)   // [B][21][64]
#define WS_O1   (WS_A1 + 43008)   // [B][17][64]
#define WS_A2   (WS_O1 + 34816)   // [B][9][128]
#define WS_Y    (WS_A2 + 36864)   // [B][128]

#define WT_C1_0 0
#define WT_C2_0 768
#define WT_DW0  3840
#define WT_C1_1 4096
#define WT_C2_1 10240
#define WT_DW1  22528
#define WT_C1_2 24576
#define WT_C2_2 49152
#define WT_DW2  98304
#define WT_TOTAL 106496

struct WSegs { const float* src[9]; int k3[9]; int colog2[9]; int off[10]; };

// ---------------------------------------------------------------------------
// K1: h = x @ pw + pb (fp32), sq = ||h||^2, zero acc; also transposes TCN
// weights into wT (independent work folded in; verified harmless in R8).
// ---------------------------------------------------------------------------
__global__ __launch_bounds__(256) void k_project(
    const float* __restrict__ x,
    const float* __restrict__ pw,
    const float* __restrict__ pb,
    WSegs S, float* __restrict__ wT,
    float* __restrict__ h, float* __restrict__ sq, float* __restrict__ acc)
{
    int gid = blockIdx.x * 256 + threadIdx.x;
    if (gid < B_ * LH_) acc[gid] = 0.f;
    if (gid < WT_TOTAL) {
#pragma unroll
        for (int s = 0; s < 9; ++s) {
            if (gid >= S.off[s] && gid < S.off[s + 1]) {
                int local = gid - S.off[s];
                int k = local >> S.colog2[s];
                int o = local & ((1 << S.colog2[s]) - 1);
                wT[gid] = S.src[s][o * S.k3[s] + k];
            }
        }
    }
    int row = gid >> 5;
    int i   = gid & 31;
    const float* xr = x + (size_t)row * C_;
    float4 x0 = *(const float4*)xr;
    float4 x1 = *(const float4*)(xr + 4);
    float hv = pb[i];
    hv = fmaf(x0.x, pw[0 * LH_ + i], hv);
    hv = fmaf(x0.y, pw[1 * LH_ + i], hv);
    hv = fmaf(x0.z, pw[2 * LH_ + i], hv);
    hv = fmaf(x0.w, pw[3 * LH_ + i], hv);
    hv = fmaf(x1.x, pw[4 * LH_ + i], hv);
    hv = fmaf(x1.y, pw[5 * LH_ + i], hv);
    hv = fmaf(x1.z, pw[6 * LH_ + i], hv);
    hv = fmaf(x1.w, pw[7 * LH_ + i], hv);
    h[(size_t)row * LH_ + i] = hv;
    float e = hv * hv;
#pragma unroll
    for (int off = 1; off < 32; off <<= 1) e += __shfl_xor(e, off, 64);
    if (i == 0) sq[row] = e;
}

// ---------------------------------------------------------------------------
// DPP full-wave min (u32) — HW-verified (R6/R7 runs).
// ---------------------------------------------------------------------------
__device__ __forceinline__ unsigned wave_min_u32(unsigned v)
{
#define DPP_MIN(ctrl) \
    v = min(v, (unsigned)__builtin_amdgcn_update_dpp((int)v, (int)v, ctrl, 0xF, 0xF, false))
    DPP_MIN(0x111);  // row_shr:1
    DPP_MIN(0x112);  // row_shr:2
    DPP_MIN(0x114);  // row_shr:4
    DPP_MIN(0x118);  // row_shr:8
    DPP_MIN(0x142);  // row_bcast:15
    DPP_MIN(0x143);  // row_bcast:31
#undef DPP_MIN
    return (unsigned)__builtin_amdgcn_readlane((int)v, 63);
}

// ---------------------------------------------------------------------------
// K2: exact R7 structure (113us, VALUBusy 85%, VGPR 68 — proven) with one
// addition: sq[s] staged into the spare LDS column (SPAD col 32), removing
// the per-s global load from the hot loop. Scalar qA/qB — DO NOT convert to
// f2/pk form (R8: compiler drops them from registers; R5: QW=4 kills occ).
// ---------------------------------------------------------------------------
#define STILE 128
#define SPAD  36

__global__ __launch_bounds__(256, 2) void k_laplace(
    const float* __restrict__ h, const float* __restrict__ sq,
    float* __restrict__ acc)
{
    __shared__ float tile[2][STILE * SPAD];   // 36 KB double buffer
    __shared__ float wacc[4 * 32];
    __shared__ float qbuf[8 * 32];

    const int tid = threadIdx.x;
    const int wv  = tid >> 6;
    const int ln  = tid & 63;
    const int b   = blockIdx.x >> 7;
    const int t0  = (blockIdx.x & 127) * 8;
    const int tA  = t0 + wv * 2;
    const int tB  = tA + 1;

    const float* hb  = h  + (size_t)b * T_ * LH_;
    const float* sqb = sq + b * T_;

    if (ln < 32) {
        qbuf[(wv * 2 + 0) * 32 + ln] = hb[tA * LH_ + ln];
        qbuf[(wv * 2 + 1) * 32 + ln] = hb[tB * LH_ + ln];
    }
    float qA[32], qB[32];
#pragma unroll
    for (int i = 0; i < 32; ++i) { qA[i] = hb[tA * LH_ + i]; qB[i] = hb[tB * LH_ + i]; }
    const float sqA = sqb[tA], sqB = sqb[tB];

    // stage from the lane's own coalesced slice (r = tid>>3, c4 = tid&7);
    // threads with c4==0 additionally stage sq[s] into column 32.
    const int st_r  = tid >> 3, st_c4 = tid & 7;
    auto stage = [&](int buf, int s_base) {
#pragma unroll
        for (int u = 0; u < 4; ++u) {
            int r = st_r + u * 32;
            float4 val = *(const float4*)(hb + (size_t)(s_base + r) * LH_ + st_c4 * 4);
            *(float4*)&tile[buf][r * SPAD + st_c4 * 4] = val;
            if (st_c4 == 0)
                tile[buf][r * SPAD + 32] = sqb[s_base + r];
        }
    };

    unsigned kA[16], kB[16];

    stage(0, 0);
    __syncthreads();

    for (int tl = 0; tl < T_ / STILE; ++tl) {
        const int s_base = tl * STILE;
        const int cur = tl & 1;
        if (tl + 1 < T_ / STILE) stage(cur ^ 1, s_base + STILE);
#pragma unroll
        for (int sub = 0; sub < 2; ++sub) {
            const int sr = sub * 64 + ln;
            const int s  = s_base + sr;
            const float* hs = &tile[cur][sr * SPAD];
            float dA = 0.f, dB = 0.f;
#pragma unroll
            for (int q4 = 0; q4 < 8; ++q4) {
                float4 hv4 = *(const float4*)(hs + q4 * 4);
                dA = fmaf(hv4.x, qA[q4 * 4 + 0], dA); dB = fmaf(hv4.x, qB[q4 * 4 + 0], dB);
                dA = fmaf(hv4.y, qA[q4 * 4 + 1], dA); dB = fmaf(hv4.y, qB[q4 * 4 + 1], dB);
                dA = fmaf(hv4.z, qA[q4 * 4 + 2], dA); dB = fmaf(hv4.z, qB[q4 * 4 + 2], dB);
                dA = fmaf(hv4.w, qA[q4 * 4 + 3], dA); dB = fmaf(hv4.w, qB[q4 * 4 + 3], dB);
            }
            const float sqs = hs[32];                 // LDS, was global sqb[s]
            float d2A = fmaxf(sqA + sqs - 2.f * dA, 0.f);
            float d2B = fmaxf(sqB + sqs - 2.f * dB, 0.f);
            unsigned keyA = (__float_as_uint(d2A) & 0xFFFFFC00u) | (unsigned)s;
            unsigned keyB = (__float_as_uint(d2B) & 0xFFFFFC00u) | (unsigned)s;
            if (s == tA) keyA = 0xFFFFFC00u | (unsigned)s;
            if (s == tB) keyB = 0xFFFFFC00u | (unsigned)s;
            kA[tl * 2 + sub] = keyA;
            kB[tl * 2 + sub] = keyB;
        }
        __syncthreads();
    }

    float racc = 0.f;

    auto process = [&](unsigned (&ku)[16], int qslot) {
        int   sk[K_];
        float wk[K_];
        unsigned g2[4];
#pragma unroll
        for (int g = 0; g < 4; ++g)
            g2[g] = min(min(ku[4 * g], ku[4 * g + 1]), min(ku[4 * g + 2], ku[4 * g + 3]));
#pragma unroll
        for (int r = 0; r < K_; ++r) {
            unsigned m  = min(min(g2[0], g2[1]), min(g2[2], g2[3]));
            unsigned mu = wave_min_u32(m);            // wave-uniform, pure VALU
            int s_win = (int)(mu & 1023u);
            sk[r] = s_win;
            wk[r] = __expf(-0.5f * __uint_as_float(mu & 0xFFFFFC00u));
            const int  c = s_win >> 6;                // SGPR -> scalar branch
            const bool winlane = ((s_win & 63) == ln);
#pragma unroll
            for (int cc = 0; cc < 16; ++cc) if (cc == c) {
                ku[cc] = winlane ? 0xFFFFFFFFu : ku[cc];
                const int g = cc >> 2;
                g2[g] = min(min(ku[4 * g], ku[4 * g + 1]), min(ku[4 * g + 2], ku[4 * g + 3]));
            }
        }
        const int i = ln & 31;
        const float qi = qbuf[qslot * 32 + i];
        float W = 0.f, sm = 0.f;
#pragma unroll
        for (int k = 0; k < K_; ++k) {
            W += wk[k];
            sm = fmaf(wk[k], hb[(size_t)sk[k] * LH_ + i], sm);
        }
        sm *= __builtin_amdgcn_rcpf(W + 1e-8f);
        float z  = qi - sm;
        float ex = __expf(2.f * z);                   // tanh(z) = 1 - 2/(e^{2z}+1)
        racc += 1.f - 2.f * __builtin_amdgcn_rcpf(ex + 1.f);
    };

    process(kA, wv * 2 + 0);
    process(kB, wv * 2 + 1);

    if (ln < 32) wacc[wv * 32 + ln] = racc;
    __syncthreads();
    if (tid < 32) {
        float tot = wacc[tid] + wacc[32 + tid] + wacc[64 + tid] + wacc[96 + tid];
        atomicAdd(&acc[b * LH_ + tid], tot);
    }
}

// ---------------------------------------------------------------------------
// TCN stages + head (unchanged, proven)
// ---------------------------------------------------------------------------
template<int CI, int CO, int DIL, int ROWS>
__global__ __launch_bounds__(256) void k_conv(
    const float* __restrict__ in, int in_bs, int in_roff,
    const float* __restrict__ wT, const float* __restrict__ bias,
    float* __restrict__ out)
{
    const int e = blockIdx.x * 256 + threadIdx.x;
    const int b = blockIdx.y;
    if (e >= ROWS * CO) return;
    const int r = e / CO, o = e % CO;
    const float* inb = in + (size_t)b * in_bs + (size_t)in_roff * CI;
    float s = bias[o];
    for (int i = 0; i < CI; ++i)
#pragma unroll
        for (int j = 0; j < 3; ++j)
            s = fmaf(wT[(i * 3 + j) * CO + o], inb[(r + DIL * j) * CI + i], s);
    out[(size_t)b * (ROWS * CO) + e] = fmaxf(s, 0.f);
}

template<int CI, int CO, int DIL, int ROWS, int RCI>
__global__ __launch_bounds__(256) void k_convres(
    const float* __restrict__ in, int in_bs,
    const float* __restrict__ wT2, const float* __restrict__ b2,
    const float* __restrict__ res, int res_bs, int res_roff,
    const float* __restrict__ wTd, const float* __restrict__ db,
    float* __restrict__ out)
{
    const int e = blockIdx.x * 256 + threadIdx.x;
    const int b = blockIdx.y;
    if (e >= ROWS * CO) return;
    const int r = e / CO, o = e % CO;
    const float* inb = in + (size_t)b * in_bs;
    float s = b2[o];
    for (int i = 0; i < CI; ++i)
#pragma unroll
        for (int j = 0; j < 3; ++j)
            s = fmaf(wT2[(i * 3 + j) * CO + o], inb[(r + DIL * j) * CI + i], s);
    s = fmaxf(s, 0.f);
    const float* rb = res + (size_t)b * res_bs + (size_t)(res_roff + r) * RCI;
    float rs = db[o];
    for (int i = 0; i < RCI; ++i)
        rs = fmaf(wTd[i * CO + o], rb[i], rs);
    out[(size_t)b * (ROWS * CO) + e] = fmaxf(s + rs, 0.f);
}

struct HeadW {
    const float *ow, *ob, *head_w, *head_b;
    const float *f1w, *f1b, *f2w, *f2b, *r1w, *r1b, *r2w, *r2b;
};

__global__ __launch_bounds__(256) void k_head(
    const float* __restrict__ y, const float* __restrict__ acc,
    HeadW hw, float* __restrict__ out)
{
    const int b = blockIdx.x, tid = threadIdx.x;
    __shared__ float yv[128], v96[96], h1[256], h2[256], h3[128];

    if (tid < 128) yv[tid] = y[b * 128 + tid];
    else if (tid < 160) {
        int j = tid - 128;
        float s = hw.ob[j];
        for (int i = 0; i < 32; ++i)
            s = fmaf(acc[b * 32 + i] * (1.f / 1024.f), hw.ow[i * 32 + j], s);
        v96[j] = s;
    }
    __syncthreads();
    if (tid < 64) {
        float s = hw.head_b[tid];
        for (int i = 0; i < 128; ++i)
            s = fmaf(yv[i], hw.head_w[i * 64 + tid], s);
        v96[32 + tid] = s;
    }
    __syncthreads();
    {
        float s = hw.f1b[tid];
        for (int i = 0; i < 96; ++i)
            s = fmaf(v96[i], hw.f1w[i * 256 + tid], s);
        h1[tid] = fmaxf(s, 0.f);
    }
    __syncthreads();
    {
        float s = hw.f2b[tid];
        for (int i = 0; i < 256; ++i)
            s = fmaf(h1[i], hw.f2w[i * 256 + tid], s);
        h2[tid] = fmaxf(s, 0.f);
    }
    __syncthreads();
    if (tid < 128) {
        float s = hw.r1b[tid];
        for (int i = 0; i < 256; ++i)
            s = fmaf(h2[i], hw.r1w[i * 128 + tid], s);
        h3[tid] = fmaxf(s, 0.f);
    }
    __syncthreads();
    if (tid < 10) {
        float s = hw.r2b[tid];
        for (int i = 0; i < 128; ++i)
            s = fmaf(h3[i], hw.r2w[i * 10 + tid], s);
        out[b * 10 + tid] = s;
    }
}

// ---------------------------------------------------------------------------
extern "C" void kernel_launch(void* const* d_in, const int* in_sizes, int n_in,
                              void* d_out, int out_size, void* d_ws, size_t ws_size,
                              hipStream_t stream)
{
    const float* x  = (const float*)d_in[0];
    const float* pw = (const float*)d_in[1];
    const float* pb = (const float*)d_in[2];

    const float* c1w0 = (const float*)d_in[5];  const float* c1b0 = (const float*)d_in[6];
    const float* c2w0 = (const float*)d_in[7];  const float* c2b0 = (const float*)d_in[8];
    const float* dw0  = (const float*)d_in[9];  const float* db0  = (const float*)d_in[10];
    const float* c1w1 = (const float*)d_in[11]; const float* c1b1 = (const float*)d_in[12];
    const float* c2w1 = (const float*)d_in[13]; const float* c2b1 = (const float*)d_in[14];
    const float* dw1  = (const float*)d_in[15]; const float* db1  = (const float*)d_in[16];
    const float* c1w2 = (const float*)d_in[17]; const float* c1b2 = (const float*)d_in[18];
    const float* c2w2 = (const float*)d_in[19]; const float* c2b2 = (const float*)d_in[20];
    const float* dw2  = (const float*)d_in[21]; const float* db2  = (const float*)d_in[22];

    HeadW hw = { (const float*)d_in[3],  (const float*)d_in[4],
                 (const float*)d_in[23], (const float*)d_in[24],
                 (const float*)d_in[25], (const float*)d_in[26],
                 (const float*)d_in[27], (const float*)d_in[28],
                 (const float*)d_in[29], (const float*)d_in[30],
                 (const float*)d_in[31], (const float*)d_in[32] };

    float* W   = (float*)d_ws;
    float* h   = W + WS_H;
    float* sq  = W + WS_SQ;
    float* acc = W + WS_ACC;
    float* wT  = W + WS_WT;
    float* a0  = W + WS_A0;
    float* o0  = W + WS_O0;
    float* a1  = W + WS_A1;
    float* o1  = W + WS_O1;
    float* a2  = W + WS_A2;
    float* y   = W + WS_Y;

    WSegs S;
    const float* srcs[9] = {c1w0, c2w0, dw0, c1w1, c2w1, dw1, c1w2, c2w2, dw2};
    const int k3s[9]   = {24, 96, 8, 96, 192, 32, 192, 384, 64};
    const int col2[9]  = {5, 5, 5, 6, 6, 6, 7, 7, 7};
    const int offs[10] = {WT_C1_0, WT_C2_0, WT_DW0, WT_C1_1, WT_C2_1, WT_DW1,
                          WT_C1_2, WT_C2_2, WT_DW2, WT_TOTAL};
    for (int i = 0; i < 9; ++i) { S.src[i] = srcs[i]; S.k3[i] = k3s[i]; S.colog2[i] = col2[i]; }
    for (int i = 0; i < 10; ++i) S.off[i] = offs[i];

    k_project<<<(B_ * T_ * LH_) / 256, 256, 0, stream>>>(x, pw, pb, S, wT, h, sq, acc);

    k_conv<8, 32, 1, 27><<<dim3(4, B_), 256, 0, stream>>>(
        x, T_ * C_, 995, wT + WT_C1_0, c1b0, a0);
    k_convres<32, 32, 1, 25, 8><<<dim3(4, B_), 256, 0, stream>>>(
        a0, 27 * 32, wT + WT_C2_0, c2b0, x, T_ * C_, 999, wT + WT_DW0, db0, o0);
    k_conv<32, 64, 2, 21><<<dim3(6, B_), 256, 0, stream>>>(
        o0, 25 * 32, 0, wT + WT_C1_1, c1b1, a1);
    k_convres<64, 64, 2, 17, 32><<<dim3(5, B_), 256, 0, stream>>>(
        a1, 21 * 64, wT + WT_C2_1, c2b1, o0, 25 * 32, 8, wT + WT_DW1, db1, o1);
    k_conv<64, 128, 4, 9><<<dim3(5, B_), 256, 0, stream>>>(
        o1, 17 * 64, 0, wT + WT_C1_2, c1b2, a2);
    k_convres<128, 128, 4, 1, 64><<<dim3(1, B_), 256, 0, stream>>>(
        a2, 9 * 128, wT + WT_C2_2, c2b2, o1, 17 * 64, 16, wT + WT_DW2, db2, y);

    k_laplace<<<(B_ * T_) / 8, 256, 0, stream>>>(h, sq, acc);
    k_head<<<B_, 256, 0, stream>>>(y, acc, hw, (float*)d_out);
}

// Round 10
// 330.534 us; speedup vs baseline: 1.0160x; 1.0160x over previous
//
#include <hip/hip_runtime.h>
#include <hip/hip_bf16.h>

#define B_  32
#define T_  1024
#define C_  8
#define K_  10
#define LH_ 32

// ---------------------------------------------------------------------------
// workspace layout (floats)
// ---------------------------------------------------------------------------
#define WS_H    0
#define WS_SQ   1048576            // B*T*32
#define WS_ACC  (WS_SQ + 32768)
#define WS_WT   (WS_ACC + 1024)   // transposed weights, 106496 floats
#define WS_A0   (WS_WT + 106496)  // [B][27][32]
#define WS_O0   (WS_A0 + 27648)   // [B][25][32]
#define WS_A1   (WS_O0 + 25600)   // [B][21][64]
#define WS_O1   (WS_A1 + 43008)   // [B][17][64]
#define WS_A2   (WS_O1 + 34816)   // [B][9][128]
#define WS_Y    (WS_A2 + 36864)   // [B][128]

#define WT_C1_0 0
#define WT_C2_0 768
#define WT_DW0  3840
#define WT_C1_1 4096
#define WT_C2_1 10240
#define WT_DW1  22528
#define WT_C1_2 24576
#define WT_C2_2 49152
#define WT_DW2  98304
#define WT_TOTAL 106496

struct WSegs { const float* src[9]; int k3[9]; int colog2[9]; int off[10]; };

// ---------------------------------------------------------------------------
// K1: h = x @ pw + pb (fp32), sq = ||h||^2, zero acc; + TCN weight transpose.
// ---------------------------------------------------------------------------
__global__ __launch_bounds__(256) void k_project(
    const float* __restrict__ x,
    const float* __restrict__ pw,
    const float* __restrict__ pb,
    WSegs S, float* __restrict__ wT,
    float* __restrict__ h, float* __restrict__ sq, float* __restrict__ acc)
{
    int gid = blockIdx.x * 256 + threadIdx.x;
    if (gid < B_ * LH_) acc[gid] = 0.f;
    if (gid < WT_TOTAL) {
#pragma unroll
        for (int s = 0; s < 9; ++s) {
            if (gid >= S.off[s] && gid < S.off[s + 1]) {
                int local = gid - S.off[s];
                int k = local >> S.colog2[s];
                int o = local & ((1 << S.colog2[s]) - 1);
                wT[gid] = S.src[s][o * S.k3[s] + k];
            }
        }
    }
    int row = gid >> 5;
    int i   = gid & 31;
    const float* xr = x + (size_t)row * C_;
    float4 x0 = *(const float4*)xr;
    float4 x1 = *(const float4*)(xr + 4);
    float hv = pb[i];
    hv = fmaf(x0.x, pw[0 * LH_ + i], hv);
    hv = fmaf(x0.y, pw[1 * LH_ + i], hv);
    hv = fmaf(x0.z, pw[2 * LH_ + i], hv);
    hv = fmaf(x0.w, pw[3 * LH_ + i], hv);
    hv = fmaf(x1.x, pw[4 * LH_ + i], hv);
    hv = fmaf(x1.y, pw[5 * LH_ + i], hv);
    hv = fmaf(x1.z, pw[6 * LH_ + i], hv);
    hv = fmaf(x1.w, pw[7 * LH_ + i], hv);
    h[(size_t)row * LH_ + i] = hv;
    float e = hv * hv;
#pragma unroll
    for (int off = 1; off < 32; off <<= 1) e += __shfl_xor(e, off, 64);
    if (i == 0) sq[row] = e;
}

// ---------------------------------------------------------------------------
// DPP full-wave min (u32) — HW-verified (R6/R7).
// ---------------------------------------------------------------------------
__device__ __forceinline__ unsigned wave_min_u32(unsigned v)
{
#define DPP_MIN(ctrl) \
    v = min(v, (unsigned)__builtin_amdgcn_update_dpp((int)v, (int)v, ctrl, 0xF, 0xF, false))
    DPP_MIN(0x111);  // row_shr:1
    DPP_MIN(0x112);  // row_shr:2
    DPP_MIN(0x114);  // row_shr:4
    DPP_MIN(0x118);  // row_shr:8
    DPP_MIN(0x142);  // row_bcast:15
    DPP_MIN(0x143);  // row_bcast:31
#undef DPP_MIN
    return (unsigned)__builtin_amdgcn_readlane((int)v, 63);
}

// ---------------------------------------------------------------------------
// K2: R7 structure (113us proven). sq staged in a COMPACT separate LDS array
// (bank = index mod 32 -> 2 lanes/bank, free). NOT a stride-36 column
// (R9: 8-way conflict, 1.5M conflict cycles). Scalar qA/qB (R8: f2 form
// gets dropped from registers; R5: QW=4 kills occupancy).
// ---------------------------------------------------------------------------
#define STILE 128
#define SPAD  36

__global__ __launch_bounds__(256, 2) void k_laplace(
    const float* __restrict__ h, const float* __restrict__ sq,
    float* __restrict__ acc)
{
    __shared__ float tile[2][STILE * SPAD];   // 36 KB double buffer
    __shared__ float sqt[2][STILE];           // compact sq tiles (1 KB)
    __shared__ float wacc[4 * 32];
    __shared__ float qbuf[8 * 32];

    const int tid = threadIdx.x;
    const int wv  = tid >> 6;
    const int ln  = tid & 63;
    const int b   = blockIdx.x >> 7;
    const int t0  = (blockIdx.x & 127) * 8;
    const int tA  = t0 + wv * 2;
    const int tB  = tA + 1;

    const float* hb  = h  + (size_t)b * T_ * LH_;
    const float* sqb = sq + b * T_;

    if (ln < 32) {
        qbuf[(wv * 2 + 0) * 32 + ln] = hb[tA * LH_ + ln];
        qbuf[(wv * 2 + 1) * 32 + ln] = hb[tB * LH_ + ln];
    }
    float qA[32], qB[32];
#pragma unroll
    for (int i = 0; i < 32; ++i) { qA[i] = hb[tA * LH_ + i]; qB[i] = hb[tB * LH_ + i]; }
    const float sqA = sqb[tA], sqB = sqb[tB];

    // stage from the lane's own coalesced slice (r = tid>>3, c4 = tid&7);
    // c4==0 threads also stage sq[s] into the compact array.
    const int st_r  = tid >> 3, st_c4 = tid & 7;
    auto stage = [&](int buf, int s_base) {
#pragma unroll
        for (int u = 0; u < 4; ++u) {
            int r = st_r + u * 32;
            float4 val = *(const float4*)(hb + (size_t)(s_base + r) * LH_ + st_c4 * 4);
            *(float4*)&tile[buf][r * SPAD + st_c4 * 4] = val;
            if (st_c4 == 0)
                sqt[buf][r] = sqb[s_base + r];
        }
    };

    unsigned kA[16], kB[16];

    stage(0, 0);
    __syncthreads();

    for (int tl = 0; tl < T_ / STILE; ++tl) {
        const int s_base = tl * STILE;
        const int cur = tl & 1;
        if (tl + 1 < T_ / STILE) stage(cur ^ 1, s_base + STILE);
#pragma unroll
        for (int sub = 0; sub < 2; ++sub) {
            const int sr = sub * 64 + ln;
            const int s  = s_base + sr;
            const float* hs = &tile[cur][sr * SPAD];
            float dA = 0.f, dB = 0.f;
#pragma unroll
            for (int q4 = 0; q4 < 8; ++q4) {
                float4 hv4 = *(const float4*)(hs + q4 * 4);
                dA = fmaf(hv4.x, qA[q4 * 4 + 0], dA); dB = fmaf(hv4.x, qB[q4 * 4 + 0], dB);
                dA = fmaf(hv4.y, qA[q4 * 4 + 1], dA); dB = fmaf(hv4.y, qB[q4 * 4 + 1], dB);
                dA = fmaf(hv4.z, qA[q4 * 4 + 2], dA); dB = fmaf(hv4.z, qB[q4 * 4 + 2], dB);
                dA = fmaf(hv4.w, qA[q4 * 4 + 3], dA); dB = fmaf(hv4.w, qB[q4 * 4 + 3], dB);
            }
            const float sqs = sqt[cur][sr];           // bank = sr mod 32, free
            float d2A = fmaxf(sqA + sqs - 2.f * dA, 0.f);
            float d2B = fmaxf(sqB + sqs - 2.f * dB, 0.f);
            unsigned keyA = (__float_as_uint(d2A) & 0xFFFFFC00u) | (unsigned)s;
            unsigned keyB = (__float_as_uint(d2B) & 0xFFFFFC00u) | (unsigned)s;
            if (s == tA) keyA = 0xFFFFFC00u | (unsigned)s;
            if (s == tB) keyB = 0xFFFFFC00u | (unsigned)s;
            kA[tl * 2 + sub] = keyA;
            kB[tl * 2 + sub] = keyB;
        }
        __syncthreads();
    }

    float racc = 0.f;

    auto process = [&](unsigned (&ku)[16], int qslot) {
        int   sk[K_];
        float wk[K_];
        unsigned g2[4];
#pragma unroll
        for (int g = 0; g < 4; ++g)
            g2[g] = min(min(ku[4 * g], ku[4 * g + 1]), min(ku[4 * g + 2], ku[4 * g + 3]));
#pragma unroll
        for (int r = 0; r < K_; ++r) {
            unsigned m  = min(min(g2[0], g2[1]), min(g2[2], g2[3]));
            unsigned mu = wave_min_u32(m);            // wave-uniform, pure VALU
            int s_win = (int)(mu & 1023u);
            sk[r] = s_win;
            wk[r] = __expf(-0.5f * __uint_as_float(mu & 0xFFFFFC00u));
            const int  c = s_win >> 6;                // SGPR -> scalar branch
            const bool winlane = ((s_win & 63) == ln);
#pragma unroll
            for (int cc = 0; cc < 16; ++cc) if (cc == c) {
                ku[cc] = winlane ? 0xFFFFFFFFu : ku[cc];
                const int g = cc >> 2;
                g2[g] = min(min(ku[4 * g], ku[4 * g + 1]), min(ku[4 * g + 2], ku[4 * g + 3]));
            }
        }
        const int i = ln & 31;
        const float qi = qbuf[qslot * 32 + i];
        float W = 0.f, sm = 0.f;
#pragma unroll
        for (int k = 0; k < K_; ++k) {
            W += wk[k];
            sm = fmaf(wk[k], hb[(size_t)sk[k] * LH_ + i], sm);
        }
        sm *= __builtin_amdgcn_rcpf(W + 1e-8f);
        float z  = qi - sm;
        float ex = __expf(2.f * z);                   // tanh(z) = 1 - 2/(e^{2z}+1)
        racc += 1.f - 2.f * __builtin_amdgcn_rcpf(ex + 1.f);
    };

    process(kA, wv * 2 + 0);
    process(kB, wv * 2 + 1);

    if (ln < 32) wacc[wv * 32 + ln] = racc;
    __syncthreads();
    if (tid < 32) {
        float tot = wacc[tid] + wacc[32 + tid] + wacc[64 + tid] + wacc[96 + tid];
        atomicAdd(&acc[b * LH_ + tid], tot);
    }
}

// ---------------------------------------------------------------------------
// TCN stages + head (unchanged, proven)
// ---------------------------------------------------------------------------
template<int CI, int CO, int DIL, int ROWS>
__global__ __launch_bounds__(256) void k_conv(
    const float* __restrict__ in, int in_bs, int in_roff,
    const float* __restrict__ wT, const float* __restrict__ bias,
    float* __restrict__ out)
{
    const int e = blockIdx.x * 256 + threadIdx.x;
    const int b = blockIdx.y;
    if (e >= ROWS * CO) return;
    const int r = e / CO, o = e % CO;
    const float* inb = in + (size_t)b * in_bs + (size_t)in_roff * CI;
    float s = bias[o];
    for (int i = 0; i < CI; ++i)
#pragma unroll
        for (int j = 0; j < 3; ++j)
            s = fmaf(wT[(i * 3 + j) * CO + o], inb[(r + DIL * j) * CI + i], s);
    out[(size_t)b * (ROWS * CO) + e] = fmaxf(s, 0.f);
}

template<int CI, int CO, int DIL, int ROWS, int RCI>
__global__ __launch_bounds__(256) void k_convres(
    const float* __restrict__ in, int in_bs,
    const float* __restrict__ wT2, const float* __restrict__ b2,
    const float* __restrict__ res, int res_bs, int res_roff,
    const float* __restrict__ wTd, const float* __restrict__ db,
    float* __restrict__ out)
{
    const int e = blockIdx.x * 256 + threadIdx.x;
    const int b = blockIdx.y;
    if (e >= ROWS * CO) return;
    const int r = e / CO, o = e % CO;
    const float* inb = in + (size_t)b * in_bs;
    float s = b2[o];
    for (int i = 0; i < CI; ++i)
#pragma unroll
        for (int j = 0; j < 3; ++j)
            s = fmaf(wT2[(i * 3 + j) * CO + o], inb[(r + DIL * j) * CI + i], s);
    s = fmaxf(s, 0.f);
    const float* rb = res + (size_t)b * res_bs + (size_t)(res_roff + r) * RCI;
    float rs = db[o];
    for (int i = 0; i < RCI; ++i)
        rs = fmaf(wTd[i * CO + o], rb[i], rs);
    out[(size_t)b * (ROWS * CO) + e] = fmaxf(s + rs, 0.f);
}

struct HeadW {
    const float *ow, *ob, *head_w, *head_b;
    const float *f1w, *f1b, *f2w, *f2b, *r1w, *r1b, *r2w, *r2b;
};

__global__ __launch_bounds__(256) void k_head(
    const float* __restrict__ y, const float* __restrict__ acc,
    HeadW hw, float* __restrict__ out)
{
    const int b = blockIdx.x, tid = threadIdx.x;
    __shared__ float yv[128], v96[96], h1[256], h2[256], h3[128];

    if (tid < 128) yv[tid] = y[b * 128 + tid];
    else if (tid < 160) {
        int j = tid - 128;
        float s = hw.ob[j];
        for (int i = 0; i < 32; ++i)
            s = fmaf(acc[b * 32 + i] * (1.f / 1024.f), hw.ow[i * 32 + j], s);
        v96[j] = s;
    }
    __syncthreads();
    if (tid < 64) {
        float s = hw.head_b[tid];
        for (int i = 0; i < 128; ++i)
            s = fmaf(yv[i], hw.head_w[i * 64 + tid], s);
        v96[32 + tid] = s;
    }
    __syncthreads();
    {
        float s = hw.f1b[tid];
        for (int i = 0; i < 96; ++i)
            s = fmaf(v96[i], hw.f1w[i * 256 + tid], s);
        h1[tid] = fmaxf(s, 0.f);
    }
    __syncthreads();
    {
        float s = hw.f2b[tid];
        for (int i = 0; i < 256; ++i)
            s = fmaf(h1[i], hw.f2w[i * 256 + tid], s);
        h2[tid] = fmaxf(s, 0.f);
    }
    __syncthreads();
    if (tid < 128) {
        float s = hw.r1b[tid];
        for (int i = 0; i < 256; ++i)
            s = fmaf(h2[i], hw.r1w[i * 128 + tid], s);
        h3[tid] = fmaxf(s, 0.f);
    }
    __syncthreads();
    if (tid < 10) {
        float s = hw.r2b[tid];
        for (int i = 0; i < 128; ++i)
            s = fmaf(h3[i], hw.r2w[i * 10 + tid], s);
        out[b * 10 + tid] = s;
    }
}

// ---------------------------------------------------------------------------
extern "C" void kernel_launch(void* const* d_in, const int* in_sizes, int n_in,
                              void* d_out, int out_size, void* d_ws, size_t ws_size,
                              hipStream_t stream)
{
    const float* x  = (const float*)d_in[0];
    const float* pw = (const float*)d_in[1];
    const float* pb = (const float*)d_in[2];

    const float* c1w0 = (const float*)d_in[5];  const float* c1b0 = (const float*)d_in[6];
    const float* c2w0 = (const float*)d_in[7];  const float* c2b0 = (const float*)d_in[8];
    const float* dw0  = (const float*)d_in[9];  const float* db0  = (const float*)d_in[10];
    const float* c1w1 = (const float*)d_in[11]; const float* c1b1 = (const float*)d_in[12];
    const float* c2w1 = (const float*)d_in[13]; const float* c2b1 = (const float*)d_in[14];
    const float* dw1  = (const float*)d_in[15]; const float* db1  = (const float*)d_in[16];
    const float* c1w2 = (const float*)d_in[17]; const float* c1b2 = (const float*)d_in[18];
    const float* c2w2 = (const float*)d_in[19]; const float* c2b2 = (const float*)d_in[20];
    const float* dw2  = (const float*)d_in[21]; const float* db2  = (const float*)d_in[22];

    HeadW hw = { (const float*)d_in[3],  (const float*)d_in[4],
                 (const float*)d_in[23], (const float*)d_in[24],
                 (const float*)d_in[25], (const float*)d_in[26],
                 (const float*)d_in[27], (const float*)d_in[28],
                 (const float*)d_in[29], (const float*)d_in[30],
                 (const float*)d_in[31], (const float*)d_in[32] };

    float* W   = (float*)d_ws;
    float* h   = W + WS_H;
    float* sq  = W + WS_SQ;
    float* acc = W + WS_ACC;
    float* wT  = W + WS_WT;
    float* a0  = W + WS_A0;
    float* o0  = W + WS_O0;
    float* a1  = W + WS_A1;
    float* o1  = W + WS_O1;
    float* a2  = W + WS_A2;
    float* y   = W + WS_Y;

    WSegs S;
    const float* srcs[9] = {c1w0, c2w0, dw0, c1w1, c2w1, dw1, c1w2, c2w2, dw2};
    const int k3s[9]   = {24, 96, 8, 96, 192, 32, 192, 384, 64};
    const int col2[9]  = {5, 5, 5, 6, 6, 6, 7, 7, 7};
    const int offs[10] = {WT_C1_0, WT_C2_0, WT_DW0, WT_C1_1, WT_C2_1, WT_DW1,
                          WT_C1_2, WT_C2_2, WT_DW2, WT_TOTAL};
    for (int i = 0; i < 9; ++i) { S.src[i] = srcs[i]; S.k3[i] = k3s[i]; S.colog2[i] = col2[i]; }
    for (int i = 0; i < 10; ++i) S.off[i] = offs[i];

    k_project<<<(B_ * T_ * LH_) / 256, 256, 0, stream>>>(x, pw, pb, S, wT, h, sq, acc);

    k_conv<8, 32, 1, 27><<<dim3(4, B_), 256, 0, stream>>>(
        x, T_ * C_, 995, wT + WT_C1_0, c1b0, a0);
    k_convres<32, 32, 1, 25, 8><<<dim3(4, B_), 256, 0, stream>>>(
        a0, 27 * 32, wT + WT_C2_0, c2b0, x, T_ * C_, 999, wT + WT_DW0, db0, o0);
    k_conv<32, 64, 2, 21><<<dim3(6, B_), 256, 0, stream>>>(
        o0, 25 * 32, 0, wT + WT_C1_1, c1b1, a1);
    k_convres<64, 64, 2, 17, 32><<<dim3(5, B_), 256, 0, stream>>>(
        a1, 21 * 64, wT + WT_C2_1, c2b1, o0, 25 * 32, 8, wT + WT_DW1, db1, o1);
    k_conv<64, 128, 4, 9><<<dim3(5, B_), 256, 0, stream>>>(
        o1, 17 * 64, 0, wT + WT_C1_2, c1b2, a2);
    k_convres<128, 128, 4, 1, 64><<<dim3(1, B_), 256, 0, stream>>>(
        a2, 9 * 128, wT + WT_C2_2, c2b2, o1, 17 * 64, 16, wT + WT_DW2, db2, y);

    k_laplace<<<(B_ * T_) / 8, 256, 0, stream>>>(h, sq, acc);
    k_head<<<B_, 256, 0, stream>>>(y, acc, hw, (float*)d_out);
}

// Round 11
// 291.380 us; speedup vs baseline: 1.1525x; 1.1344x over previous
//
#include <hip/hip_runtime.h>
#include <hip/hip_bf16.h>

#define B_  32
#define T_  1024
#define C_  8
#define K_  10
#define LH_ 32

// ---------------------------------------------------------------------------
// workspace layout (floats)
// ---------------------------------------------------------------------------
#define WS_H    0
#define WS_SQ   1048576            // B*T*32
#define WS_ACC  (WS_SQ + 32768)
#define WS_WT   (WS_ACC + 1024)   // transposed weights, 106496 floats
#define WS_A0   (WS_WT + 106496)  // [B][27][32]
#define WS_O0   (WS_A0 + 27648)   // [B][25][32]
#define WS_A1   (WS_O0 + 25600)   // [B][21][64]
#define WS_O1   (WS_A1 + 43008)   // [B][17][64]
#define WS_A2   (WS_O1 + 34816)   // [B][9][128]
#define WS_Y    (WS_A2 + 36864)   // [B][128]

#define WT_C1_0 0
#define WT_C2_0 768
#define WT_DW0  3840
#define WT_C1_1 4096
#define WT_C2_1 10240
#define WT_DW1  22528
#define WT_C1_2 24576
#define WT_C2_2 49152
#define WT_DW2  98304
#define WT_TOTAL 106496

struct WSegs { const float* src[9]; int k3[9]; int colog2[9]; int off[10]; };

// ---------------------------------------------------------------------------
// K1: h = x @ pw + pb (fp32), sq = ||h||^2, zero acc; + TCN weight transpose.
// ---------------------------------------------------------------------------
__global__ __launch_bounds__(256) void k_project(
    const float* __restrict__ x,
    const float* __restrict__ pw,
    const float* __restrict__ pb,
    WSegs S, float* __restrict__ wT,
    float* __restrict__ h, float* __restrict__ sq, float* __restrict__ acc)
{
    int gid = blockIdx.x * 256 + threadIdx.x;
    if (gid < B_ * LH_) acc[gid] = 0.f;
    if (gid < WT_TOTAL) {
#pragma unroll
        for (int s = 0; s < 9; ++s) {
            if (gid >= S.off[s] && gid < S.off[s + 1]) {
                int local = gid - S.off[s];
                int k = local >> S.colog2[s];
                int o = local & ((1 << S.colog2[s]) - 1);
                wT[gid] = S.src[s][o * S.k3[s] + k];
            }
        }
    }
    int row = gid >> 5;
    int i   = gid & 31;
    const float* xr = x + (size_t)row * C_;
    float4 x0 = *(const float4*)xr;
    float4 x1 = *(const float4*)(xr + 4);
    float hv = pb[i];
    hv = fmaf(x0.x, pw[0 * LH_ + i], hv);
    hv = fmaf(x0.y, pw[1 * LH_ + i], hv);
    hv = fmaf(x0.z, pw[2 * LH_ + i], hv);
    hv = fmaf(x0.w, pw[3 * LH_ + i], hv);
    hv = fmaf(x1.x, pw[4 * LH_ + i], hv);
    hv = fmaf(x1.y, pw[5 * LH_ + i], hv);
    hv = fmaf(x1.z, pw[6 * LH_ + i], hv);
    hv = fmaf(x1.w, pw[7 * LH_ + i], hv);
    h[(size_t)row * LH_ + i] = hv;
    float e = hv * hv;
#pragma unroll
    for (int off = 1; off < 32; off <<= 1) e += __shfl_xor(e, off, 64);
    if (i == 0) sq[row] = e;
}

// ---------------------------------------------------------------------------
// DPP full-wave min (u32) — HW-verified (R6/R7).
// ---------------------------------------------------------------------------
__device__ __forceinline__ unsigned wave_min_u32(unsigned v)
{
#define DPP_MIN(ctrl) \
    v = min(v, (unsigned)__builtin_amdgcn_update_dpp((int)v, (int)v, ctrl, 0xF, 0xF, false))
    DPP_MIN(0x111);  // row_shr:1
    DPP_MIN(0x112);  // row_shr:2
    DPP_MIN(0x114);  // row_shr:4
    DPP_MIN(0x118);  // row_shr:8
    DPP_MIN(0x142);  // row_bcast:15
    DPP_MIN(0x143);  // row_bcast:31
#undef DPP_MIN
    return (unsigned)__builtin_amdgcn_readlane((int)v, 63);
}

// ---------------------------------------------------------------------------
// K2: EXACT R7 kernel — measured 113us, VALUBusy 85%, VGPR 68, conflicts 0.
// Local optimum; all 6 perturbations regressed:
//  - QW=4 (R5): 128 query VGPRs -> occupancy cliff, 163us
//  - f2/pk dots (R8): allocator drops query arrays from regs, 146us
//  - whole-h-in-LDS 1024-thr (R6): spill to scratch, 1075us
//  - sq in stride-36 LDS column (R9): 8-way bank conflict, 159us
//  - sq in compact LDS array (R10): staging drain kills dbuf overlap, 152us
// DO NOT TOUCH: scalar qA/qB, global sqb[s] in hot loop, 256 thr, (256,2).
// ---------------------------------------------------------------------------
#define STILE 128
#define SPAD  36

__global__ __launch_bounds__(256, 2) void k_laplace(
    const float* __restrict__ h, const float* __restrict__ sq,
    float* __restrict__ acc)
{
    __shared__ float tile[2][STILE * SPAD];   // 36 KB double buffer
    __shared__ float wacc[4 * 32];
    __shared__ float qbuf[8 * 32];

    const int tid = threadIdx.x;
    const int wv  = tid >> 6;
    const int ln  = tid & 63;
    const int b   = blockIdx.x >> 7;
    const int t0  = (blockIdx.x & 127) * 8;
    const int tA  = t0 + wv * 2;
    const int tB  = tA + 1;

    const float* hb  = h  + (size_t)b * T_ * LH_;
    const float* sqb = sq + b * T_;

    if (ln < 32) {
        qbuf[(wv * 2 + 0) * 32 + ln] = hb[tA * LH_ + ln];
        qbuf[(wv * 2 + 1) * 32 + ln] = hb[tB * LH_ + ln];
    }
    float qA[32], qB[32];
#pragma unroll
    for (int i = 0; i < 32; ++i) { qA[i] = hb[tA * LH_ + i]; qB[i] = hb[tB * LH_ + i]; }
    const float sqA = sqb[tA], sqB = sqb[tB];

    // stage from the lane's own coalesced slice (r = tid>>3, c4 = tid&7)
    const int st_r  = tid >> 3, st_c4 = tid & 7;
    auto stage = [&](int buf, int s_base) {
#pragma unroll
        for (int u = 0; u < 4; ++u) {
            int r = st_r + u * 32;
            float4 val = *(const float4*)(hb + (size_t)(s_base + r) * LH_ + st_c4 * 4);
            *(float4*)&tile[buf][r * SPAD + st_c4 * 4] = val;
        }
    };

    unsigned kA[16], kB[16];

    stage(0, 0);
    __syncthreads();

    for (int tl = 0; tl < T_ / STILE; ++tl) {
        const int s_base = tl * STILE;
        const int cur = tl & 1;
        if (tl + 1 < T_ / STILE) stage(cur ^ 1, s_base + STILE);
#pragma unroll
        for (int sub = 0; sub < 2; ++sub) {
            const int sr = sub * 64 + ln;
            const int s  = s_base + sr;
            const float* hs = &tile[cur][sr * SPAD];
            float dA = 0.f, dB = 0.f;
#pragma unroll
            for (int q4 = 0; q4 < 8; ++q4) {
                float4 hv4 = *(const float4*)(hs + q4 * 4);
                dA = fmaf(hv4.x, qA[q4 * 4 + 0], dA); dB = fmaf(hv4.x, qB[q4 * 4 + 0], dB);
                dA = fmaf(hv4.y, qA[q4 * 4 + 1], dA); dB = fmaf(hv4.y, qB[q4 * 4 + 1], dB);
                dA = fmaf(hv4.z, qA[q4 * 4 + 2], dA); dB = fmaf(hv4.z, qB[q4 * 4 + 2], dB);
                dA = fmaf(hv4.w, qA[q4 * 4 + 3], dA); dB = fmaf(hv4.w, qB[q4 * 4 + 3], dB);
            }
            const float sqs = sqb[s];
            float d2A = fmaxf(sqA + sqs - 2.f * dA, 0.f);
            float d2B = fmaxf(sqB + sqs - 2.f * dB, 0.f);
            unsigned keyA = (__float_as_uint(d2A) & 0xFFFFFC00u) | (unsigned)s;
            unsigned keyB = (__float_as_uint(d2B) & 0xFFFFFC00u) | (unsigned)s;
            if (s == tA) keyA = 0xFFFFFC00u | (unsigned)s;
            if (s == tB) keyB = 0xFFFFFC00u | (unsigned)s;
            kA[tl * 2 + sub] = keyA;
            kB[tl * 2 + sub] = keyB;
        }
        __syncthreads();
    }

    float racc = 0.f;

    auto process = [&](unsigned (&ku)[16], int qslot) {
        int   sk[K_];
        float wk[K_];
        unsigned g2[4];
#pragma unroll
        for (int g = 0; g < 4; ++g)
            g2[g] = min(min(ku[4 * g], ku[4 * g + 1]), min(ku[4 * g + 2], ku[4 * g + 3]));
#pragma unroll
        for (int r = 0; r < K_; ++r) {
            unsigned m  = min(min(g2[0], g2[1]), min(g2[2], g2[3]));
            unsigned mu = wave_min_u32(m);            // wave-uniform, pure VALU
            int s_win = (int)(mu & 1023u);
            sk[r] = s_win;
            wk[r] = __expf(-0.5f * __uint_as_float(mu & 0xFFFFFC00u));
            const int  c = s_win >> 6;                // SGPR -> scalar branch
            const bool winlane = ((s_win & 63) == ln);
#pragma unroll
            for (int cc = 0; cc < 16; ++cc) if (cc == c) {
                ku[cc] = winlane ? 0xFFFFFFFFu : ku[cc];
                const int g = cc >> 2;
                g2[g] = min(min(ku[4 * g], ku[4 * g + 1]), min(ku[4 * g + 2], ku[4 * g + 3]));
            }
        }
        const int i = ln & 31;
        const float qi = qbuf[qslot * 32 + i];
        float W = 0.f, sm = 0.f;
#pragma unroll
        for (int k = 0; k < K_; ++k) {
            W += wk[k];
            sm = fmaf(wk[k], hb[(size_t)sk[k] * LH_ + i], sm);
        }
        sm *= __builtin_amdgcn_rcpf(W + 1e-8f);
        float z  = qi - sm;
        float ex = __expf(2.f * z);                   // tanh(z) = 1 - 2/(e^{2z}+1)
        racc += 1.f - 2.f * __builtin_amdgcn_rcpf(ex + 1.f);
    };

    process(kA, wv * 2 + 0);
    process(kB, wv * 2 + 1);

    if (ln < 32) wacc[wv * 32 + ln] = racc;
    __syncthreads();
    if (tid < 32) {
        float tot = wacc[tid] + wacc[32 + tid] + wacc[64 + tid] + wacc[96 + tid];
        atomicAdd(&acc[b * LH_ + tid], tot);
    }
}

// ---------------------------------------------------------------------------
// TCN stages + head (unchanged, proven)
// ---------------------------------------------------------------------------
template<int CI, int CO, int DIL, int ROWS>
__global__ __launch_bounds__(256) void k_conv(
    const float* __restrict__ in, int in_bs, int in_roff,
    const float* __restrict__ wT, const float* __restrict__ bias,
    float* __restrict__ out)
{
    const int e = blockIdx.x * 256 + threadIdx.x;
    const int b = blockIdx.y;
    if (e >= ROWS * CO) return;
    const int r = e / CO, o = e % CO;
    const float* inb = in + (size_t)b * in_bs + (size_t)in_roff * CI;
    float s = bias[o];
    for (int i = 0; i < CI; ++i)
#pragma unroll
        for (int j = 0; j < 3; ++j)
            s = fmaf(wT[(i * 3 + j) * CO + o], inb[(r + DIL * j) * CI + i], s);
    out[(size_t)b * (ROWS * CO) + e] = fmaxf(s, 0.f);
}

template<int CI, int CO, int DIL, int ROWS, int RCI>
__global__ __launch_bounds__(256) void k_convres(
    const float* __restrict__ in, int in_bs,
    const float* __restrict__ wT2, const float* __restrict__ b2,
    const float* __restrict__ res, int res_bs, int res_roff,
    const float* __restrict__ wTd, const float* __restrict__ db,
    float* __restrict__ out)
{
    const int e = blockIdx.x * 256 + threadIdx.x;
    const int b = blockIdx.y;
    if (e >= ROWS * CO) return;
    const int r = e / CO, o = e % CO;
    const float* inb = in + (size_t)b * in_bs;
    float s = b2[o];
    for (int i = 0; i < CI; ++i)
#pragma unroll
        for (int j = 0; j < 3; ++j)
            s = fmaf(wT2[(i * 3 + j) * CO + o], inb[(r + DIL * j) * CI + i], s);
    s = fmaxf(s, 0.f);
    const float* rb = res + (size_t)b * res_bs + (size_t)(res_roff + r) * RCI;
    float rs = db[o];
    for (int i = 0; i < RCI; ++i)
        rs = fmaf(wTd[i * CO + o], rb[i], rs);
    out[(size_t)b * (ROWS * CO) + e] = fmaxf(s + rs, 0.f);
}

struct HeadW {
    const float *ow, *ob, *head_w, *head_b;
    const float *f1w, *f1b, *f2w, *f2b, *r1w, *r1b, *r2w, *r2b;
};

__global__ __launch_bounds__(256) void k_head(
    const float* __restrict__ y, const float* __restrict__ acc,
    HeadW hw, float* __restrict__ out)
{
    const int b = blockIdx.x, tid = threadIdx.x;
    __shared__ float yv[128], v96[96], h1[256], h2[256], h3[128];

    if (tid < 128) yv[tid] = y[b * 128 + tid];
    else if (tid < 160) {
        int j = tid - 128;
        float s = hw.ob[j];
        for (int i = 0; i < 32; ++i)
            s = fmaf(acc[b * 32 + i] * (1.f / 1024.f), hw.ow[i * 32 + j], s);
        v96[j] = s;
    }
    __syncthreads();
    if (tid < 64) {
        float s = hw.head_b[tid];
        for (int i = 0; i < 128; ++i)
            s = fmaf(yv[i], hw.head_w[i * 64 + tid], s);
        v96[32 + tid] = s;
    }
    __syncthreads();
    {
        float s = hw.f1b[tid];
        for (int i = 0; i < 96; ++i)
            s = fmaf(v96[i], hw.f1w[i * 256 + tid], s);
        h1[tid] = fmaxf(s, 0.f);
    }
    __syncthreads();
    {
        float s = hw.f2b[tid];
        for (int i = 0; i < 256; ++i)
            s = fmaf(h1[i], hw.f2w[i * 256 + tid], s);
        h2[tid] = fmaxf(s, 0.f);
    }
    __syncthreads();
    if (tid < 128) {
        float s = hw.r1b[tid];
        for (int i = 0; i < 256; ++i)
            s = fmaf(h2[i], hw.r1w[i * 128 + tid], s);
        h3[tid] = fmaxf(s, 0.f);
    }
    __syncthreads();
    if (tid < 10) {
        float s = hw.r2b[tid];
        for (int i = 0; i < 128; ++i)
            s = fmaf(h3[i], hw.r2w[i * 10 + tid], s);
        out[b * 10 + tid] = s;
    }
}

// ---------------------------------------------------------------------------
extern "C" void kernel_launch(void* const* d_in, const int* in_sizes, int n_in,
                              void* d_out, int out_size, void* d_ws, size_t ws_size,
                              hipStream_t stream)
{
    const float* x  = (const float*)d_in[0];
    const float* pw = (const float*)d_in[1];
    const float* pb = (const float*)d_in[2];

    const float* c1w0 = (const float*)d_in[5];  const float* c1b0 = (const float*)d_in[6];
    const float* c2w0 = (const float*)d_in[7];  const float* c2b0 = (const float*)d_in[8];
    const float* dw0  = (const float*)d_in[9];  const float* db0  = (const float*)d_in[10];
    const float* c1w1 = (const float*)d_in[11]; const float* c1b1 = (const float*)d_in[12];
    const float* c2w1 = (const float*)d_in[13]; const float* c2b1 = (const float*)d_in[14];
    const float* dw1  = (const float*)d_in[15]; const float* db1  = (const float*)d_in[16];
    const float* c1w2 = (const float*)d_in[17]; const float* c1b2 = (const float*)d_in[18];
    const float* c2w2 = (const float*)d_in[19]; const float* c2b2 = (const float*)d_in[20];
    const float* dw2  = (const float*)d_in[21]; const float* db2  = (const float*)d_in[22];

    HeadW hw = { (const float*)d_in[3],  (const float*)d_in[4],
                 (const float*)d_in[23], (const float*)d_in[24],
                 (const float*)d_in[25], (const float*)d_in[26],
                 (const float*)d_in[27], (const float*)d_in[28],
                 (const float*)d_in[29], (const float*)d_in[30],
                 (const float*)d_in[31], (const float*)d_in[32] };

    float* W   = (float*)d_ws;
    float* h   = W + WS_H;
    float* sq  = W + WS_SQ;
    float* acc = W + WS_ACC;
    float* wT  = W + WS_WT;
    float* a0  = W + WS_A0;
    float* o0  = W + WS_O0;
    float* a1  = W + WS_A1;
    float* o1  = W + WS_O1;
    float* a2  = W + WS_A2;
    float* y   = W + WS_Y;

    WSegs S;
    const float* srcs[9] = {c1w0, c2w0, dw0, c1w1, c2w1, dw1, c1w2, c2w2, dw2};
    const int k3s[9]   = {24, 96, 8, 96, 192, 32, 192, 384, 64};
    const int col2[9]  = {5, 5, 5, 6, 6, 6, 7, 7, 7};
    const int offs[10] = {WT_C1_0, WT_C2_0, WT_DW0, WT_C1_1, WT_C2_1, WT_DW1,
                          WT_C1_2, WT_C2_2, WT_DW2, WT_TOTAL};
    for (int i = 0; i < 9; ++i) { S.src[i] = srcs[i]; S.k3[i] = k3s[i]; S.colog2[i] = col2[i]; }
    for (int i = 0; i < 10; ++i) S.off[i] = offs[i];

    k_project<<<(B_ * T_ * LH_) / 256, 256, 0, stream>>>(x, pw, pb, S, wT, h, sq, acc);

    k_conv<8, 32, 1, 27><<<dim3(4, B_), 256, 0, stream>>>(
        x, T_ * C_, 995, wT + WT_C1_0, c1b0, a0);
    k_convres<32, 32, 1, 25, 8><<<dim3(4, B_), 256, 0, stream>>>(
        a0, 27 * 32, wT + WT_C2_0, c2b0, x, T_ * C_, 999, wT + WT_DW0, db0, o0);
    k_conv<32, 64, 2, 21><<<dim3(6, B_), 256, 0, stream>>>(
        o0, 25 * 32, 0, wT + WT_C1_1, c1b1, a1);
    k_convres<64, 64, 2, 17, 32><<<dim3(5, B_), 256, 0, stream>>>(
        a1, 21 * 64, wT + WT_C2_1, c2b1, o0, 25 * 32, 8, wT + WT_DW1, db1, o1);
    k_conv<64, 128, 4, 9><<<dim3(5, B_), 256, 0, stream>>>(
        o1, 17 * 64, 0, wT + WT_C1_2, c1b2, a2);
    k_convres<128, 128, 4, 1, 64><<<dim3(1, B_), 256, 0, stream>>>(
        a2, 9 * 128, wT + WT_C2_2, c2b2, o1, 17 * 64, 16, wT + WT_DW2, db2, y);

    k_laplace<<<(B_ * T_) / 8, 256, 0, stream>>>(h, sq, acc);
    k_head<<<B_, 256, 0, stream>>>(y, acc, hw, (float*)d_out);
}